// Round 30
// baseline (59.652 us; speedup 1.0000x reference)
//
#include <hip/hip_runtime.h>
#include <hip/hip_fp8.h>
#include <math.h>

constexpr int NN = 10000;
constexpr int EE = 320000;
constexpr int H  = 4;
constexpr int D  = 64;
constexpr int C  = 16;
constexpr int IN = 256;
constexpr int HD = H * D;   // 256
constexpr int STRIDE = 128; // fixed CSR row stride (max in-degree ~65 << 128)
constexpr int NBKT = 64;    // LN-sum buckets (r15 lesson: 1-line atomics serialize)
constexpr int CPAD = 32;    // counter pad: one counter per 128B line (r29: -5.8us)

typedef __attribute__((ext_vector_type(8))) short bf16x8;
typedef __attribute__((ext_vector_type(4))) float f32x4;

__device__ __forceinline__ unsigned short f2b(float x) {
    unsigned int b = __float_as_uint(x);
    return (unsigned short)((b + 0x7FFFu + ((b >> 16) & 1u)) >> 16); // RNE bf16
}
__device__ __forceinline__ float b2f(unsigned short u) {
    return __uint_as_float((unsigned int)u << 16);
}
// fp8 e4m3 encode (HW convert on gfx950; saturating)
__device__ __forceinline__ unsigned char f2q(float x) {
#if __has_builtin(__builtin_amdgcn_cvt_pk_fp8_f32)
    return (unsigned char)(__builtin_amdgcn_cvt_pk_fp8_f32(x, x, 0, false) & 0xFF);
#else
    __hip_fp8_e4m3 q(x); return (unsigned char)q.__x;
#endif
}
// fp8 e4m3 decode, byte S of word w
template<int S>
__device__ __forceinline__ float q2f(unsigned int w) {
#if __has_builtin(__builtin_amdgcn_cvt_f32_fp8)
    return __builtin_amdgcn_cvt_f32_fp8(w, S);
#else
    __hip_fp8_e4m3 q; q.__x = (unsigned char)((w >> (8 * S)) & 0xFF); return (float)q;
#endif
}

// ---- workspace layout (float-element offsets) ----
constexpr long OFF_FB   = 0;                               // N*HD bf16 (residual path)
constexpr long OFF_EL   = OFF_FB   + (long)NN * HD / 2;    // N*H
constexpr long OFF_ER   = OFF_EL   + (long)NN * H;         // N*H
constexpr long OFF_F1   = OFF_ER   + (long)NN * H;         // N*H
constexpr long OFF_F2   = OFF_F1   + (long)NN * H;         // N*H
constexpr long OFF_AGGB = OFF_F2   + (long)NN * H;         // N*HD bf16
constexpr long OFF_PRED = OFF_AGGB + (long)NN * HD / 2;    // N   (int)
constexpr long OFF_SSRC = OFF_PRED + (long)NN;             // N*STRIDE (int) packed src|pred<<16
constexpr long OFF_DEGI = OFF_SSRC + (long)NN * STRIDE;    // N*CPAD (int, zeroed by k_pack)
constexpr long OFF_BKT  = OFF_DEGI + (long)NN * CPAD;      // NBKT*4 f32 (zeroed by k_pack)
constexpr long OFF_WP   = (OFF_BKT + NBKT * 4 + 3) & ~3L;  // 65536 bf16 (16B-aligned)
constexpr long OFF_FQ   = OFF_WP + 32768;                  // N*HD fp8 gather table (bytes)
constexpr long WS_END   = OFF_FQ + (long)NN * HD / 4;

constexpr int GEMB = NN / 16;          // 625 MFMA-gemm blocks (FIRST: fast-retiring)
constexpr int PB   = (NN + 255) / 256; // 40 pred blocks (in k_pack)
constexpr int CB   = (EE + 255) / 256; // 1250 count+scatter blocks
constexpr int ZB   = (NN * CPAD / 4 + 255) / 256; // 313 zero blocks (int4 stores)

// k_pack roles: [0,32) W->B-frag pack; [32,32+ZB) zero padded deg counters
// (+buckets); [32+ZB,...) pred=argmax(logits).
__global__ __launch_bounds__(256) void k_pack(const float* __restrict__ W,
                                              const float* __restrict__ logits,
                                              unsigned short* __restrict__ wp,
                                              int* __restrict__ pred,
                                              int* __restrict__ deg_i,
                                              float* __restrict__ bkt) {
    int bid = blockIdx.x;
    int t = threadIdx.x;
    if (bid < 32) {
        int tg = bid * 256 + t; // [0, 8192)
        int l  = tg & 63;
        int ct = (tg >> 6) & 3;
        int ks = (tg >> 8) & 7;
        int w  = tg >> 11;
        int col = w * 64 + ct * 16 + (l & 15);
        int kb  = ks * 32 + (l >> 4) * 8;
        unsigned short v[8];
#pragma unroll
        for (int i = 0; i < 8; ++i) v[i] = f2b(W[(long)(kb + i) * HD + col]);
        ushort4* p = (ushort4*)(wp + (long)tg * 8);
        p[0] = make_ushort4(v[0], v[1], v[2], v[3]);
        p[1] = make_ushort4(v[4], v[5], v[6], v[7]);
    } else if (bid < 32 + ZB) {
        long i4 = ((long)(bid - 32) * 256 + t) * 4;
        if (i4 < (long)NN * CPAD) *(int4*)(deg_i + i4) = make_int4(0, 0, 0, 0);
        if (bid == 32) bkt[t] = 0.f; // t < 256 == NBKT*4
    } else {
        int n = (bid - 32 - ZB) * 256 + t;
        if (n < NN) {
            const float* row = logits + (long)n * C;
            float best = row[0]; int bi = 0;
#pragma unroll
            for (int c = 1; c < C; ++c) { float v = row[c]; if (v > best) { best = v; bi = c; } }
            pred[n] = bi;
        }
    }
}

// fused main kernel. GEMM blocks [0,GEMB) FIRST (fast-retiring; r27 lesson).
// Count+scatter follows with line-padded counters (r29). GEMM epilogue writes
// featb (bf16, residual path) AND featq (fp8 e4m3, 2.5MB gather table that
// fits XCD L2 and halves k_agg's edge-gather traffic).
__global__ __launch_bounds__(256) void k_main(const float* __restrict__ hin,
                                              const unsigned short* __restrict__ wp,
                                              const float* __restrict__ al,
                                              const float* __restrict__ ar,
                                              const int*   __restrict__ src,
                                              const int*   __restrict__ dst,
                                              const int*   __restrict__ pred,
                                              unsigned short* __restrict__ featb,
                                              unsigned char* __restrict__ featq,
                                              float* __restrict__ el,
                                              float* __restrict__ er,
                                              int*   __restrict__ deg_i,
                                              int*   __restrict__ ssrc) {
    int bid = blockIdx.x;
    int t = threadIdx.x;
    if (bid < GEMB) {
        // ---- MFMA GEMM ----
        int tile = bid;
        int w = t >> 6, l = t & 63;
        int g = l >> 4, fr = l & 15;

        f32x4 acc[4];
#pragma unroll
        for (int ct = 0; ct < 4; ++ct) acc[ct] = (f32x4){0.f, 0.f, 0.f, 0.f};

        const unsigned short* wpw = wp + (long)w * 8 * 4 * 64 * 8;
        const float* hrow = hin + (long)(tile * 16 + fr) * IN + g * 8;

        for (int ks = 0; ks < 8; ++ks) {
            float4 a0 = *(const float4*)(hrow + ks * 32);
            float4 a1 = *(const float4*)(hrow + ks * 32 + 4);
            bf16x8 af;
            af[0] = (short)f2b(a0.x); af[1] = (short)f2b(a0.y);
            af[2] = (short)f2b(a0.z); af[3] = (short)f2b(a0.w);
            af[4] = (short)f2b(a1.x); af[5] = (short)f2b(a1.y);
            af[6] = (short)f2b(a1.z); af[7] = (short)f2b(a1.w);
#pragma unroll
            for (int ct = 0; ct < 4; ++ct) {
                bf16x8 bfr = *(const bf16x8*)(wpw + (((long)ks * 4 + ct) * 64 + l) * 8);
                acc[ct] = __builtin_amdgcn_mfma_f32_16x16x32_bf16(af, bfr, acc[ct], 0, 0, 0);
            }
        }

        float aLr[4], aRr[4];
#pragma unroll
        for (int ct = 0; ct < 4; ++ct) {
            aLr[ct] = al[w * 64 + ct * 16 + fr];
            aRr[ct] = ar[w * 64 + ct * 16 + fr];
        }
#pragma unroll
        for (int j = 0; j < 4; ++j) {
            int row = tile * 16 + g * 4 + j;
            float vl = 0.f, vr = 0.f;
#pragma unroll
            for (int ct = 0; ct < 4; ++ct) {
                float v = acc[ct][j];
                featb[(long)row * HD + w * 64 + ct * 16 + fr] = f2b(v);
                featq[(long)row * HD + w * 64 + ct * 16 + fr] = f2q(v);
                vl = fmaf(v, aLr[ct], vl);
                vr = fmaf(v, aRr[ct], vr);
            }
            vl += __shfl_xor(vl, 1); vl += __shfl_xor(vl, 2);
            vl += __shfl_xor(vl, 4); vl += __shfl_xor(vl, 8);
            vr += __shfl_xor(vr, 1); vr += __shfl_xor(vr, 2);
            vr += __shfl_xor(vr, 4); vr += __shfl_xor(vr, 8);
            if (fr == 0) {
                el[(long)row * H + w] = vl;
                er[(long)row * H + w] = vr;
            }
        }
    } else {
        // ---- count + scatter (line-padded counters) ----
        int e = (bid - GEMB) * 256 + t;
        if (e < EE) {
            int s = src[e];
            int d = dst[e];
            int r = atomicAdd(&deg_i[(long)d * CPAD], 1);
            ssrc[(long)d * STRIDE + r] = s | (pred[s] << 16);
        }
    }
}

// one wave per dst node, edge-PAIR main loop: lanes 0-31 gather edge k's
// 256B fp8 featq row at 8B/lane, lanes 32-63 edge k+1. fp8 decode via HW
// cvt (table fits XCD L2: traffic halved vs bf16). f1 in prologue; class
// sums via per-wave LDS histogram.
#define EDGE2(st, kk) { \
    int sp0 = __builtin_amdgcn_readlane(spreg[st], (kk)); \
    int sp1 = __builtin_amdgcn_readlane(spreg[st], (kk) + 1); \
    int sph = half ? sp1 : sp0; \
    int s_  = sph & 0xFFFF; \
    float wa = __shfl(wreg[st], (chead << 4) | ((kk) + half)); \
    const uint2 fq = *(const uint2*)(featq + (long)s_ * HD + jj * 8); \
    acc[0] = fmaf(wa, q2f<0>(fq.x), acc[0]); \
    acc[1] = fmaf(wa, q2f<1>(fq.x), acc[1]); \
    acc[2] = fmaf(wa, q2f<2>(fq.x), acc[2]); \
    acc[3] = fmaf(wa, q2f<3>(fq.x), acc[3]); \
    acc[4] = fmaf(wa, q2f<0>(fq.y), acc[4]); \
    acc[5] = fmaf(wa, q2f<1>(fq.y), acc[5]); \
    acc[6] = fmaf(wa, q2f<2>(fq.y), acc[6]); \
    acc[7] = fmaf(wa, q2f<3>(fq.y), acc[7]); \
}

__global__ __launch_bounds__(256) void k_agg(const int* __restrict__ deg_i,
                                             const int* __restrict__ ssrc,
                                             const float* __restrict__ el,
                                             const float* __restrict__ er,
                                             const unsigned char* __restrict__ featq,
                                             const int* __restrict__ pred,
                                             unsigned short* __restrict__ aggb,
                                             float* __restrict__ f1,
                                             float* __restrict__ f2,
                                             float* __restrict__ bkt) {
    __shared__ float red[4][4];
    __shared__ float chist[4][64];
    int lane = threadIdx.x & 63;
    int wv = threadIdx.x >> 6;
    int n = blockIdx.x * 4 + wv; // grid = NN/4 exactly
    int deg = deg_i[(long)n * CPAD];
    long beg = (long)n * STRIDE;
    int hidx = lane >> 4, cidx = lane & 15;
    int half = lane >> 5, jj = lane & 31;
    int chead = jj >> 3; // head of this lane's channel group (for EDGE2)
    float Rh = er[(long)n * H + hidx];
    int pd = pred[n];
    int nst = (deg + 15) >> 4; // <= 8 by STRIDE bound

    chist[wv][lane] = 0.f;

    float wreg[8]; int spreg[8];
    float dsum = 0.f, f1a = 0.f;
#pragma unroll
    for (int st = 0; st < 8; ++st) {
        wreg[st] = 0.f; spreg[st] = 0;
        int idx = st * 16 + cidx;
        if (st < nst && idx < deg) {
            int sp = ssrc[beg + idx];
            int s = sp & 0xFFFF;
            int ps = sp >> 16;
            float x = el[(long)s * H + hidx] + Rh;
            x = x > 0.f ? x : 0.2f * x;
            float w = __expf(x);
            wreg[st] = w;
            spreg[st] = (hidx == 0) ? sp : 0;
            f1a += (ps == pd) ? w : 0.f;
            atomicAdd(&chist[wv][(hidx << 4) | ps], w);
        }
        dsum += wreg[st];
    }

    float acc[8];
#pragma unroll
    for (int i = 0; i < 8; ++i) acc[i] = 0.f;
#pragma unroll
    for (int st = 0; st < 8; ++st) {
        if (st >= nst) break; // wave-uniform
#pragma unroll
        for (int k = 0; k < 16; k += 2) EDGE2(st, k)
    }
    // combine the two half-wave edge subsets
#pragma unroll
    for (int i = 0; i < 8; ++i) acc[i] += __shfl_xor(acc[i], 32);

    // per-head reductions over the 16-lane groups
    for (int off = 1; off < 16; off <<= 1) {
        dsum += __shfl_xor(dsum, off);
        f1a  += __shfl_xor(f1a, off);
    }
    float invh = dsum > 0.f ? 1.f / dsum : 0.f;
    float invdeg = 1.0f / (float)(deg > 0 ? deg : 1);

    // write agg: lanes 0-31, 16B each (channel group jj*8.., head jj>>3)
    float invw = __shfl(invh, chead << 4);
    if (half == 0) {
        unsigned short ob[8];
#pragma unroll
        for (int i = 0; i < 8; ++i) ob[i] = f2b(acc[i] * invw);
        ushort4* po = (ushort4*)(aggb + (long)n * HD + jj * 8);
        po[0] = make_ushort4(ob[0], ob[1], ob[2], ob[3]);
        po[1] = make_ushort4(ob[4], ob[5], ob[6], ob[7]);
    }

    float f1v = f1a * invh * invdeg;
    float ca = chist[wv][lane]; // class-cidx sum for head hidx
    float v = fmaxf(ca * invh * invdeg, 1e-5f);
    float term = -v * logf(v);
    for (int off = 1; off < 16; off <<= 1) term += __shfl_xor(term, off);
    if (cidx == 0) {
        f1[(long)n * H + hidx] = f1v;
        f2[(long)n * H + hidx] = term;
    }

    // LN partial sums -> 64-way-spread buckets (4 atomics/block)
    float c1 = (cidx == 0) ? f1v : 0.f;
    float c2 = (cidx == 0) ? term : 0.f;
    float q1 = c1 * f1v, q2 = c2 * term;
    for (int off = 1; off < 64; off <<= 1) {
        c1 += __shfl_xor(c1, off);
        q1 += __shfl_xor(q1, off);
        c2 += __shfl_xor(c2, off);
        q2 += __shfl_xor(q2, off);
    }
    if (lane == 0) { red[wv][0] = c1; red[wv][1] = q1; red[wv][2] = c2; red[wv][3] = q2; }
    __syncthreads();
    if (threadIdx.x < 4) {
        float a = red[0][threadIdx.x] + red[1][threadIdx.x]
                + red[2][threadIdx.x] + red[3][threadIdx.x];
        atomicAdd(&bkt[(blockIdx.x & (NBKT - 1)) * 4 + threadIdx.x], a);
    }
}

// fused: per-block bucket reduce -> LN stats; z/gate; final output.
// 4 elems/thread; feat (residual) and agg both read as bf16.
__global__ __launch_bounds__(256) void k_out(const unsigned short* __restrict__ featb,
                                             const unsigned short* __restrict__ aggb,
                                             const float* __restrict__ f1,
                                             const float* __restrict__ f2,
                                             const float* __restrict__ bkt,
                                             const float* __restrict__ old_z,
                                             const float* __restrict__ tau1,
                                             const float* __restrict__ tau2,
                                             const int* __restrict__ deg_i,
                                             float* __restrict__ out,
                                             float* __restrict__ zout) {
    __shared__ float sred[4];
    int lane = threadIdx.x & 63;
    int wv = threadIdx.x >> 6;
    // wave wv reduces stat wv over the 64 buckets (1KB, L2-resident)
    float pv = bkt[lane * 4 + wv];
    for (int off = 1; off < 64; off <<= 1) pv += __shfl_xor(pv, off);
    if (lane == 0) sred[wv] = pv;
    __syncthreads();

    long i4 = ((long)blockIdx.x * 256 + threadIdx.x) * 4;
    if (i4 >= (long)NN * HD) return;
    int n = (int)(i4 >> 8);
    int h = (int)((i4 >> 6) & 3);
    int t = n * H + h;
    constexpr float invNH = 1.0f / (NN * H);
    float mu1 = sred[0] * invNH, mu2 = sred[2] * invNH;
    float v1 = fmaxf(sred[1] * invNH - mu1 * mu1, 0.f);
    float v2 = fmaxf(sred[3] * invNH - mu2 * mu2, 0.f);
    float r1 = rsqrtf(v1 + 1e-5f), r2 = rsqrtf(v2 + 1e-5f);
    float nf1 = (f1[t] - mu1) * r1;
    float nf2 = (f2[t] - mu2) * r2;
    float z = (1.f / (1.f + expf(nf1 - tau1[0]))) * (1.f / (1.f + expf(nf2 - tau2[0])));
    float gate = fminf(old_z[t], z);
    if ((i4 & 63) == 0) zout[t] = z;
    int deg = deg_i[(long)n * CPAD];
    float g = gate * rsqrtf((float)(deg > 0 ? deg : 1));
    const ushort4 fb = *(const ushort4*)(featb + i4);
    const ushort4 ag = *(const ushort4*)(aggb + i4);
    float4 o;
    o.x = fmaf(g, b2f(ag.x), b2f(fb.x));
    o.y = fmaf(g, b2f(ag.y), b2f(fb.y));
    o.z = fmaf(g, b2f(ag.z), b2f(fb.z));
    o.w = fmaf(g, b2f(ag.w), b2f(fb.w));
    *(float4*)(out + i4) = o;
}

extern "C" void kernel_launch(void* const* d_in, const int* in_sizes, int n_in,
                              void* d_out, int out_size, void* d_ws, size_t ws_size,
                              hipStream_t stream) {
    const float* hin    = (const float*)d_in[0];
    const float* logits = (const float*)d_in[1];
    const float* old_z  = (const float*)d_in[2];
    const float* attn_l = (const float*)d_in[3];
    const float* attn_r = (const float*)d_in[4];
    const float* Wfc    = (const float*)d_in[5];
    const float* tau1   = (const float*)d_in[6];
    const float* tau2   = (const float*)d_in[7];
    const int*   src    = (const int*)d_in[8];
    const int*   dst    = (const int*)d_in[9];
    float* out = (float*)d_out;
    float* ws  = (float*)d_ws;

    unsigned short* featb = (unsigned short*)(ws + OFF_FB);
    unsigned short* aggb  = (unsigned short*)(ws + OFF_AGGB);
    unsigned short* wp    = (unsigned short*)(ws + OFF_WP);
    unsigned char*  featq = (unsigned char*)(ws + OFF_FQ);
    int* pred   = (int*)(ws + OFF_PRED);
    int* ssrc   = (int*)(ws + OFF_SSRC);
    int* deg_i  = (int*)(ws + OFF_DEGI);
    float* bkt  = ws + OFF_BKT;

    k_pack <<<32 + ZB + PB, 256, 0, stream>>>(Wfc, logits, wp, pred, deg_i, bkt);
    k_main <<<GEMB + CB, 256, 0, stream>>>(hin, wp, attn_l, attn_r,
                                           src, dst, pred, featb, featq,
                                           ws + OFF_EL, ws + OFF_ER,
                                           deg_i, ssrc);
    k_agg  <<<NN / 4, 256, 0, stream>>>(deg_i, ssrc, ws + OFF_EL, ws + OFF_ER,
                                        featq, pred, aggb,
                                        ws + OFF_F1, ws + OFF_F2, bkt);
    k_out  <<<(NN * HD / 4 + 255) / 256, 256, 0, stream>>>(featb, aggb,
                                                           ws + OFF_F1, ws + OFF_F2, bkt,
                                                           old_z, tau1, tau2, deg_i,
                                                           out, out + (long)NN * HD);
}

// Round 31
// 58.461 us; speedup vs baseline: 1.0204x; 1.0204x over previous
//
#include <hip/hip_runtime.h>
#include <math.h>

constexpr int NN = 10000;
constexpr int EE = 320000;
constexpr int H  = 4;
constexpr int D  = 64;
constexpr int C  = 16;
constexpr int IN = 256;
constexpr int HD = H * D;   // 256
constexpr int STRIDE = 128; // fixed CSR row stride (max in-degree ~65 << 128)
constexpr int NBKT = 64;    // LN-sum buckets (r15 lesson: 1-line atomics serialize)
constexpr int CPAD = 32;    // counter pad: one counter per 128B line (r29: -5.8us)

typedef __attribute__((ext_vector_type(8))) short bf16x8;
typedef __attribute__((ext_vector_type(4))) float f32x4;
typedef __attribute__((ext_vector_type(8))) unsigned short u16x8;

__device__ __forceinline__ unsigned short f2b(float x) {
    unsigned int b = __float_as_uint(x);
    return (unsigned short)((b + 0x7FFFu + ((b >> 16) & 1u)) >> 16); // RNE bf16
}
__device__ __forceinline__ float b2f(unsigned short u) {
    return __uint_as_float((unsigned int)u << 16);
}

// ---- workspace layout (float-element offsets) ----
constexpr long OFF_FB   = 0;                               // N*HD bf16
constexpr long OFF_EL   = OFF_FB   + (long)NN * HD / 2;    // N*H
constexpr long OFF_ER   = OFF_EL   + (long)NN * H;         // N*H
constexpr long OFF_F1   = OFF_ER   + (long)NN * H;         // N*H
constexpr long OFF_F2   = OFF_F1   + (long)NN * H;         // N*H
constexpr long OFF_AGGB = OFF_F2   + (long)NN * H;         // N*HD bf16
constexpr long OFF_PRED = OFF_AGGB + (long)NN * HD / 2;    // N   (int)
constexpr long OFF_SSRC = OFF_PRED + (long)NN;             // N*STRIDE (int) packed src|pred<<16
constexpr long OFF_DEGI = OFF_SSRC + (long)NN * STRIDE;    // N*CPAD (int, zeroed by k_pack)
constexpr long OFF_BKT  = OFF_DEGI + (long)NN * CPAD;      // NBKT*4 f32 (zeroed by k_pack)
constexpr long OFF_WP   = (OFF_BKT + NBKT * 4 + 3) & ~3L;  // 65536 bf16 (16B-aligned)
constexpr long WS_END   = OFF_WP + 32768;

constexpr int GEMB = NN / 16;          // 625 MFMA-gemm blocks (FIRST: fast-retiring)
constexpr int PB   = (NN + 255) / 256; // 40 pred blocks (in k_pack)
constexpr int CB   = (EE + 255) / 256; // 1250 count+scatter blocks
constexpr int ZB   = (NN * CPAD / 4 + 255) / 256; // 313 zero blocks (int4 stores)

// k_pack roles: [0,32) W->B-frag pack; [32,32+ZB) zero padded deg counters
// (+buckets); [32+ZB,...) pred=argmax(logits).
__global__ __launch_bounds__(256) void k_pack(const float* __restrict__ W,
                                              const float* __restrict__ logits,
                                              unsigned short* __restrict__ wp,
                                              int* __restrict__ pred,
                                              int* __restrict__ deg_i,
                                              float* __restrict__ bkt) {
    int bid = blockIdx.x;
    int t = threadIdx.x;
    if (bid < 32) {
        int tg = bid * 256 + t; // [0, 8192)
        int l  = tg & 63;
        int ct = (tg >> 6) & 3;
        int ks = (tg >> 8) & 7;
        int w  = tg >> 11;
        int col = w * 64 + ct * 16 + (l & 15);
        int kb  = ks * 32 + (l >> 4) * 8;
        unsigned short v[8];
#pragma unroll
        for (int i = 0; i < 8; ++i) v[i] = f2b(W[(long)(kb + i) * HD + col]);
        ushort4* p = (ushort4*)(wp + (long)tg * 8);
        p[0] = make_ushort4(v[0], v[1], v[2], v[3]);
        p[1] = make_ushort4(v[4], v[5], v[6], v[7]);
    } else if (bid < 32 + ZB) {
        long i4 = ((long)(bid - 32) * 256 + t) * 4;
        if (i4 < (long)NN * CPAD) *(int4*)(deg_i + i4) = make_int4(0, 0, 0, 0);
        if (bid == 32) bkt[t] = 0.f; // t < 256 == NBKT*4
    } else {
        int n = (bid - 32 - ZB) * 256 + t;
        if (n < NN) {
            const float* row = logits + (long)n * C;
            float best = row[0]; int bi = 0;
#pragma unroll
            for (int c = 1; c < C; ++c) { float v = row[c]; if (v > best) { best = v; bi = c; } }
            pred[n] = bi;
        }
    }
}

// fused main kernel. GEMM blocks [0,GEMB) FIRST (fast-retiring; r27 lesson:
// slow atomic-bound blocks first monopolize CU slots). Count+scatter blocks
// follow; counters line-padded so the TCC atomic stream hits distinct lines.
// Count atomic's return value = slot rank; fixed-stride slot table needs no
// scan; scattered value is packed src|pred<<16 (k_agg needs no pred gather).
// GEMM A-fragments: direct f32 h loads + in-register RNE bf16 conversion.
__global__ __launch_bounds__(256) void k_main(const float* __restrict__ hin,
                                              const unsigned short* __restrict__ wp,
                                              const float* __restrict__ al,
                                              const float* __restrict__ ar,
                                              const int*   __restrict__ src,
                                              const int*   __restrict__ dst,
                                              const int*   __restrict__ pred,
                                              unsigned short* __restrict__ featb,
                                              float* __restrict__ el,
                                              float* __restrict__ er,
                                              int*   __restrict__ deg_i,
                                              int*   __restrict__ ssrc) {
    int bid = blockIdx.x;
    int t = threadIdx.x;
    if (bid < GEMB) {
        // ---- MFMA GEMM ----
        int tile = bid;
        int w = t >> 6, l = t & 63;
        int g = l >> 4, fr = l & 15;

        f32x4 acc[4];
#pragma unroll
        for (int ct = 0; ct < 4; ++ct) acc[ct] = (f32x4){0.f, 0.f, 0.f, 0.f};

        const unsigned short* wpw = wp + (long)w * 8 * 4 * 64 * 8;
        const float* hrow = hin + (long)(tile * 16 + fr) * IN + g * 8;

        for (int ks = 0; ks < 8; ++ks) {
            float4 a0 = *(const float4*)(hrow + ks * 32);
            float4 a1 = *(const float4*)(hrow + ks * 32 + 4);
            bf16x8 af;
            af[0] = (short)f2b(a0.x); af[1] = (short)f2b(a0.y);
            af[2] = (short)f2b(a0.z); af[3] = (short)f2b(a0.w);
            af[4] = (short)f2b(a1.x); af[5] = (short)f2b(a1.y);
            af[6] = (short)f2b(a1.z); af[7] = (short)f2b(a1.w);
#pragma unroll
            for (int ct = 0; ct < 4; ++ct) {
                bf16x8 bfr = *(const bf16x8*)(wpw + (((long)ks * 4 + ct) * 64 + l) * 8);
                acc[ct] = __builtin_amdgcn_mfma_f32_16x16x32_bf16(af, bfr, acc[ct], 0, 0, 0);
            }
        }

        float aLr[4], aRr[4];
#pragma unroll
        for (int ct = 0; ct < 4; ++ct) {
            aLr[ct] = al[w * 64 + ct * 16 + fr];
            aRr[ct] = ar[w * 64 + ct * 16 + fr];
        }
#pragma unroll
        for (int j = 0; j < 4; ++j) {
            int row = tile * 16 + g * 4 + j;
            float vl = 0.f, vr = 0.f;
#pragma unroll
            for (int ct = 0; ct < 4; ++ct) {
                float v = acc[ct][j];
                featb[(long)row * HD + w * 64 + ct * 16 + fr] = f2b(v);
                vl = fmaf(v, aLr[ct], vl);
                vr = fmaf(v, aRr[ct], vr);
            }
            vl += __shfl_xor(vl, 1); vl += __shfl_xor(vl, 2);
            vl += __shfl_xor(vl, 4); vl += __shfl_xor(vl, 8);
            vr += __shfl_xor(vr, 1); vr += __shfl_xor(vr, 2);
            vr += __shfl_xor(vr, 4); vr += __shfl_xor(vr, 8);
            if (fr == 0) {
                el[(long)row * H + w] = vl;
                er[(long)row * H + w] = vr;
            }
        }
    } else {
        // ---- count + scatter (line-padded counters) ----
        int e = (bid - GEMB) * 256 + t;
        if (e < EE) {
            int s = src[e];
            int d = dst[e];
            int r = atomicAdd(&deg_i[(long)d * CPAD], 1);
            ssrc[(long)d * STRIDE + r] = s | (pred[s] << 16);
        }
    }
}

// one wave per dst node, edge-PAIR main loop: lanes 0-31 gather edge k's
// 512B featb row at 16B/lane (ushort8), lanes 32-63 edge k+1 — loads and
// bpermutes halve vs the per-edge version; bytes and FMAs unchanged.
// f1 accumulates in the prologue (each lane knows its own edge's pred);
// class sums via per-wave LDS histogram (ds_add_f32).
#define EDGE2(st, kk) { \
    int sp0 = __builtin_amdgcn_readlane(spreg[st], (kk)); \
    int sp1 = __builtin_amdgcn_readlane(spreg[st], (kk) + 1); \
    int sph = half ? sp1 : sp0; \
    int s_  = sph & 0xFFFF; \
    float wa = __shfl(wreg[st], (chead << 4) | ((kk) + half)); \
    const u16x8 f = *(const u16x8*)(featb + (long)s_ * HD + jj * 8); \
    acc[0] = fmaf(wa, b2f(f[0]), acc[0]); \
    acc[1] = fmaf(wa, b2f(f[1]), acc[1]); \
    acc[2] = fmaf(wa, b2f(f[2]), acc[2]); \
    acc[3] = fmaf(wa, b2f(f[3]), acc[3]); \
    acc[4] = fmaf(wa, b2f(f[4]), acc[4]); \
    acc[5] = fmaf(wa, b2f(f[5]), acc[5]); \
    acc[6] = fmaf(wa, b2f(f[6]), acc[6]); \
    acc[7] = fmaf(wa, b2f(f[7]), acc[7]); \
}

__global__ __launch_bounds__(256) void k_agg(const int* __restrict__ deg_i,
                                             const int* __restrict__ ssrc,
                                             const float* __restrict__ el,
                                             const float* __restrict__ er,
                                             const unsigned short* __restrict__ featb,
                                             const int* __restrict__ pred,
                                             unsigned short* __restrict__ aggb,
                                             float* __restrict__ f1,
                                             float* __restrict__ f2,
                                             float* __restrict__ bkt) {
    __shared__ float red[4][4];
    __shared__ float chist[4][64];
    int lane = threadIdx.x & 63;
    int wv = threadIdx.x >> 6;
    int n = blockIdx.x * 4 + wv; // grid = NN/4 exactly
    int deg = deg_i[(long)n * CPAD];
    long beg = (long)n * STRIDE;
    int hidx = lane >> 4, cidx = lane & 15;
    int half = lane >> 5, jj = lane & 31;
    int chead = jj >> 3; // head of this lane's channel group (for EDGE2)
    float Rh = er[(long)n * H + hidx];
    int pd = pred[n];
    int nst = (deg + 15) >> 4; // <= 8 by STRIDE bound

    chist[wv][lane] = 0.f;

    float wreg[8]; int spreg[8];
    float dsum = 0.f, f1a = 0.f;
#pragma unroll
    for (int st = 0; st < 8; ++st) {
        wreg[st] = 0.f; spreg[st] = 0;
        int idx = st * 16 + cidx;
        if (st < nst && idx < deg) {
            int sp = ssrc[beg + idx];
            int s = sp & 0xFFFF;
            int ps = sp >> 16;
            float x = el[(long)s * H + hidx] + Rh;
            x = x > 0.f ? x : 0.2f * x;
            float w = __expf(x);
            wreg[st] = w;
            spreg[st] = (hidx == 0) ? sp : 0;
            f1a += (ps == pd) ? w : 0.f;
            atomicAdd(&chist[wv][(hidx << 4) | ps], w);
        }
        dsum += wreg[st];
    }

    float acc[8];
#pragma unroll
    for (int i = 0; i < 8; ++i) acc[i] = 0.f;
#pragma unroll
    for (int st = 0; st < 8; ++st) {
        if (st >= nst) break; // wave-uniform
#pragma unroll
        for (int k = 0; k < 16; k += 2) EDGE2(st, k)
    }
    // combine the two half-wave edge subsets
#pragma unroll
    for (int i = 0; i < 8; ++i) acc[i] += __shfl_xor(acc[i], 32);

    // per-head reductions over the 16-lane groups
    for (int off = 1; off < 16; off <<= 1) {
        dsum += __shfl_xor(dsum, off);
        f1a  += __shfl_xor(f1a, off);
    }
    float invh = dsum > 0.f ? 1.f / dsum : 0.f;
    float invdeg = 1.0f / (float)(deg > 0 ? deg : 1);

    // write agg: lanes 0-31, 16B each (channel group jj*8.., head jj>>3)
    float invw = __shfl(invh, chead << 4);
    if (half == 0) {
        u16x8 ob;
#pragma unroll
        for (int i = 0; i < 8; ++i) ob[i] = f2b(acc[i] * invw);
        *(u16x8*)(aggb + (long)n * HD + jj * 8) = ob;
    }

    float f1v = f1a * invh * invdeg;
    float ca = chist[wv][lane]; // class-cidx sum for head hidx
    float v = fmaxf(ca * invh * invdeg, 1e-5f);
    float term = -v * logf(v);
    for (int off = 1; off < 16; off <<= 1) term += __shfl_xor(term, off);
    if (cidx == 0) {
        f1[(long)n * H + hidx] = f1v;
        f2[(long)n * H + hidx] = term;
    }

    // LN partial sums -> 64-way-spread buckets (4 atomics/block)
    float c1 = (cidx == 0) ? f1v : 0.f;
    float c2 = (cidx == 0) ? term : 0.f;
    float q1 = c1 * f1v, q2 = c2 * term;
    for (int off = 1; off < 64; off <<= 1) {
        c1 += __shfl_xor(c1, off);
        q1 += __shfl_xor(q1, off);
        c2 += __shfl_xor(c2, off);
        q2 += __shfl_xor(q2, off);
    }
    if (lane == 0) { red[wv][0] = c1; red[wv][1] = q1; red[wv][2] = c2; red[wv][3] = q2; }
    __syncthreads();
    if (threadIdx.x < 4) {
        float a = red[0][threadIdx.x] + red[1][threadIdx.x]
                + red[2][threadIdx.x] + red[3][threadIdx.x];
        atomicAdd(&bkt[(blockIdx.x & (NBKT - 1)) * 4 + threadIdx.x], a);
    }
}

// fused: per-block bucket reduce -> LN stats; z/gate; final output.
// 4 elems/thread; feat and agg both read as bf16.
__global__ __launch_bounds__(256) void k_out(const unsigned short* __restrict__ featb,
                                             const unsigned short* __restrict__ aggb,
                                             const float* __restrict__ f1,
                                             const float* __restrict__ f2,
                                             const float* __restrict__ bkt,
                                             const float* __restrict__ old_z,
                                             const float* __restrict__ tau1,
                                             const float* __restrict__ tau2,
                                             const int* __restrict__ deg_i,
                                             float* __restrict__ out,
                                             float* __restrict__ zout) {
    __shared__ float sred[4];
    int lane = threadIdx.x & 63;
    int wv = threadIdx.x >> 6;
    // wave wv reduces stat wv over the 64 buckets (1KB, L2-resident)
    float pv = bkt[lane * 4 + wv];
    for (int off = 1; off < 64; off <<= 1) pv += __shfl_xor(pv, off);
    if (lane == 0) sred[wv] = pv;
    __syncthreads();

    long i4 = ((long)blockIdx.x * 256 + threadIdx.x) * 4;
    if (i4 >= (long)NN * HD) return;
    int n = (int)(i4 >> 8);
    int h = (int)((i4 >> 6) & 3);
    int t = n * H + h;
    constexpr float invNH = 1.0f / (NN * H);
    float mu1 = sred[0] * invNH, mu2 = sred[2] * invNH;
    float v1 = fmaxf(sred[1] * invNH - mu1 * mu1, 0.f);
    float v2 = fmaxf(sred[3] * invNH - mu2 * mu2, 0.f);
    float r1 = rsqrtf(v1 + 1e-5f), r2 = rsqrtf(v2 + 1e-5f);
    float nf1 = (f1[t] - mu1) * r1;
    float nf2 = (f2[t] - mu2) * r2;
    float z = (1.f / (1.f + expf(nf1 - tau1[0]))) * (1.f / (1.f + expf(nf2 - tau2[0])));
    float gate = fminf(old_z[t], z);
    if ((i4 & 63) == 0) zout[t] = z;
    int deg = deg_i[(long)n * CPAD];
    float g = gate * rsqrtf((float)(deg > 0 ? deg : 1));
    const ushort4 fb = *(const ushort4*)(featb + i4);
    const ushort4 ag = *(const ushort4*)(aggb + i4);
    float4 o;
    o.x = fmaf(g, b2f(ag.x), b2f(fb.x));
    o.y = fmaf(g, b2f(ag.y), b2f(fb.y));
    o.z = fmaf(g, b2f(ag.z), b2f(fb.z));
    o.w = fmaf(g, b2f(ag.w), b2f(fb.w));
    *(float4*)(out + i4) = o;
}

extern "C" void kernel_launch(void* const* d_in, const int* in_sizes, int n_in,
                              void* d_out, int out_size, void* d_ws, size_t ws_size,
                              hipStream_t stream) {
    const float* hin    = (const float*)d_in[0];
    const float* logits = (const float*)d_in[1];
    const float* old_z  = (const float*)d_in[2];
    const float* attn_l = (const float*)d_in[3];
    const float* attn_r = (const float*)d_in[4];
    const float* Wfc    = (const float*)d_in[5];
    const float* tau1   = (const float*)d_in[6];
    const float* tau2   = (const float*)d_in[7];
    const int*   src    = (const int*)d_in[8];
    const int*   dst    = (const int*)d_in[9];
    float* out = (float*)d_out;
    float* ws  = (float*)d_ws;

    unsigned short* featb = (unsigned short*)(ws + OFF_FB);
    unsigned short* aggb  = (unsigned short*)(ws + OFF_AGGB);
    unsigned short* wp    = (unsigned short*)(ws + OFF_WP);
    int* pred   = (int*)(ws + OFF_PRED);
    int* ssrc   = (int*)(ws + OFF_SSRC);
    int* deg_i  = (int*)(ws + OFF_DEGI);
    float* bkt  = ws + OFF_BKT;

    k_pack <<<32 + ZB + PB, 256, 0, stream>>>(Wfc, logits, wp, pred, deg_i, bkt);
    k_main <<<GEMB + CB, 256, 0, stream>>>(hin, wp, attn_l, attn_r,
                                           src, dst, pred, featb,
                                           ws + OFF_EL, ws + OFF_ER,
                                           deg_i, ssrc);
    k_agg  <<<NN / 4, 256, 0, stream>>>(deg_i, ssrc, ws + OFF_EL, ws + OFF_ER,
                                        featb, pred, aggb,
                                        ws + OFF_F1, ws + OFF_F2, bkt);
    k_out  <<<(NN * HD / 4 + 255) / 256, 256, 0, stream>>>(featb, aggb,
                                                           ws + OFF_F1, ws + OFF_F2, bkt,
                                                           old_z, tau1, tau2, deg_i,
                                                           out, out + (long)NN * HD);
}